// Round 14
// baseline (128.837 us; speedup 1.0000x reference)
//
#include <hip/hip_runtime.h>
#include <stdint.h>

// ScaledDotProductAttention: B=16, Nq=Nk=4096, d=128, fp32 in/out, causal.
// Flash forward, bf16 MFMA 16x16x32, swapped-QK^T (lane-local softmax).
// Round-13: 4-slot LDS ring (4 x 16KB = 64KB). All piece sizes are multiples
// of 4 units, so each group = {compute 4 units in ONE basic block -> barrier
// -> stage next 4 -> vmcnt(0) -> barrier}. Cross-unit ILP inside the group
// de-serializes the LDS/MFMA/VALU pipes that per-unit barriers had locked
// into phase-coherent bursts (r6-r12 plateau: pipe-cycle SUM == wall).
// Core = r11's verified qt=2 compute; layouts = r12's verified linear prepack;
// split = r12's 2-piece + 2-way merge, cut at 64 (piece0=64, piece1=68).
// ws: Kfrag 16MB | Vfrag 16MB | Pa 8MB @32M | Ml 512KB @40M (NEED 42.5MB).

#define NB 16
#define NS 4096
#define DH 128

typedef float          fx4   __attribute__((ext_vector_type(4)));
typedef uint32_t       ux4   __attribute__((ext_vector_type(4)));
typedef __bf16         bfv8  __attribute__((ext_vector_type(8)));
typedef __bf16         bfv4  __attribute__((ext_vector_type(4)));
typedef unsigned short u16x4 __attribute__((ext_vector_type(4)));

typedef const uint32_t __attribute__((address_space(1))) glob_u32;
typedef uint32_t       __attribute__((address_space(3))) lds_u32;

__device__ __forceinline__ fx4 mfma16(bfv8 a, bfv8 b, fx4 c) {
  return __builtin_amdgcn_mfma_f32_16x16x32_bf16(a, b, c, 0, 0, 0);
}

// ---------------- fused prepass (r12-verified): K,V fp32 -> packed bf16 ----------------
// Kfrag[b][kv64][tt(4)][c(4)][lane][8]: K[b][kvb+16tt+ln16][32c+8g+e]
//   -> 32-kv unit u = kv64*2 + (tt>>1) contiguous 8KB.
// Vfrag linear: [b][kv64][c(2)][dt(8)][lane][8]: V^T row d=16dt+ln16,
//   unit u = kv64*2 + c contiguous 8KB; local kv map: e<4 -> 4g+e ;
//   e>=4 -> 16+4g+(e-4).
__global__ void __launch_bounds__(256) prepack_kernel(
    const float* __restrict__ K, const float* __restrict__ V,
    unsigned short* __restrict__ Kf, unsigned short* __restrict__ Vf) {
  __shared__ __align__(16) unsigned short tile[64][136];
  const int bid = blockIdx.x;
  const int b = bid >> 6, kvblk = bid & 63;
  const int kvb = kvblk << 6;
  const int tid = threadIdx.x;
  const size_t fbase = ((size_t)(b * 64 + kvblk)) * 8192;  // u16 units

  {
    const int tt = tid >> 6, lane = tid & 63;
    const int ln16 = lane & 15, g = lane >> 4;
    const float* kp = K + (((size_t)(b * NS + kvb + 16 * tt + ln16)) << 7) + 8 * g;
    unsigned short* op = Kf + fbase + tt * 2048 + lane * 8;
#pragma unroll
    for (int c = 0; c < 4; ++c) {
      fx4 a0 = *(const fx4*)(kp + 32 * c);
      fx4 a1 = *(const fx4*)(kp + 32 * c + 4);
      bfv8 t;
#pragma unroll
      for (int j = 0; j < 4; ++j) {
        t[j]     = (__bf16)a0[j];
        t[j + 4] = (__bf16)a1[j];
      }
      *(ux4*)(op + c * 512) = __builtin_bit_cast(ux4, t);
    }
  }

  {
    const int r = tid >> 2, cq = tid & 3;
    const float* vp = V + (((size_t)(b * NS + kvb + r)) << 7) + 32 * cq;
#pragma unroll
    for (int h = 0; h < 4; ++h) {
      fx4 f0 = *(const fx4*)(vp + 8 * h);
      fx4 f1 = *(const fx4*)(vp + 8 * h + 4);
      bfv8 t;
#pragma unroll
      for (int j = 0; j < 4; ++j) {
        t[j]     = (__bf16)f0[j];
        t[j + 4] = (__bf16)f1[j];
      }
      *(ux4*)&tile[r][32 * cq + 8 * h] = __builtin_bit_cast(ux4, t);
    }
  }
  __syncthreads();
  {
    const int dt = tid >> 5, c = (tid >> 4) & 1, ln16 = tid & 15;
    const int d = 16 * dt + ln16;
    unsigned short* op = Vf + fbase + c * 4096 + dt * 512 + ln16 * 8;
#pragma unroll
    for (int g = 0; g < 4; ++g) {
      unsigned short e[8];
#pragma unroll
      for (int j = 0; j < 4; ++j) {
        e[j]     = tile[32 * c + 4 * g + j][d];
        e[j + 4] = tile[32 * c + 16 + 4 * g + j][d];
      }
      *(ux4*)(op + g * 128) = *(const ux4*)e;  // lane*8 = (g*16+ln16)*8
    }
  }
}

// ---------------- main: causal flash attention, 4-slot ring ----------------
// Units = 32-kv. Tile t needs 4t+4 units (mult of 4). Split (grid 512):
//   wid<256:  piece = big tile T=31-v, units [0,64), mode 1 (raw f32 -> O)
//   wid>=256: piece = T units [64,128-4v) mode 2 (bf16 -> Pa), then full
//             small tile v (4v+4 units) mode 0. 64 vs 68 units per block.
__global__ void __launch_bounds__(256, 2) attn_kernel(
    const float* __restrict__ Q, const unsigned short* __restrict__ Kf,
    const unsigned short* __restrict__ Vf, float* __restrict__ O,
    unsigned short* __restrict__ Pa, float* __restrict__ Ml, int split) {
  __shared__ __align__(16) unsigned char sm[65536];  // 4 slots x (K 8K | V 8K)

  const int wid  = blockIdx.x;
  const int tid  = threadIdx.x;
  const int w    = tid >> 6;
  const int lane = tid & 63;
  const int g    = lane >> 4;
  const int ln16 = lane & 15;

  int b, t, u0, un, mode;
  int t1 = 0, u1b = 0, again = 0;

  if (split) {
    const int half = wid >> 8;
    const int v    = (wid >> 4) & 15;
    b = wid & 15;                     // wid%8 = b%8 -> XCD pin
    t = 31 - v;                       // big tile
    if (half == 0) {
      u0 = 0; un = 64; mode = 1;
    } else {
      u0 = 64; un = 128 - 4 * v; mode = 2;
      t1 = v; u1b = 4 * v + 4; again = 1;
    }
  } else {  // fallback: full tiles, paired big/small, direct write
    const int half = wid >> 8, ii = wid & 255;
    b = ii & 15;
    const int qi = ii >> 4;
    t = half ? qi : 31 - qi;
    u0 = 0; un = 4 * t + 4; mode = 0;
  }

  const float SCALE = 0.12753102f;  // log2(e)/sqrt(128): exp2-domain scores
  const fx4 z4 = {0.f, 0.f, 0.f, 0.f};

  const unsigned char* kfB = (const unsigned char*)Kf + (size_t)b * 1048576;
  const unsigned char* vfB = (const unsigned char*)Vf + (size_t)b * 1048576;

  // stage 32-kv unit jb into ring slot at byte offset so (16KB: K 8K | V 8K).
  // K and V units are contiguous 8KB. Wave w moves 2KB of each (4 loads).
#define STAGE(jb, so)                                                          \
  do {                                                                         \
    const unsigned char* gk = kfB + (size_t)(jb) * 8192;                       \
    const unsigned char* gv = vfB + (size_t)(jb) * 8192;                       \
    __builtin_amdgcn_global_load_lds((glob_u32*)(gk + w * 2048 + lane * 16),   \
        (lds_u32*)(sm + (so) + w * 2048), 16, 0, 0);                           \
    __builtin_amdgcn_global_load_lds((glob_u32*)(gk + w * 2048 + 1024 + lane * 16), \
        (lds_u32*)(sm + (so) + w * 2048 + 1024), 16, 0, 0);                    \
    __builtin_amdgcn_global_load_lds((glob_u32*)(gv + w * 2048 + lane * 16),   \
        (lds_u32*)(sm + (so) + 8192 + w * 2048), 16, 0, 0);                    \
    __builtin_amdgcn_global_load_lds((glob_u32*)(gv + w * 2048 + 1024 + lane * 16), \
        (lds_u32*)(sm + (so) + 8192 + w * 2048 + 1024), 16, 0, 0);             \
  } while (0)

  // r11-verified qt=2 compute core for one 32-kv unit from ring slot `so`.
#define COMPUTE(jb, so)                                                        \
  do {                                                                         \
    const unsigned char* kb = sm + (so);                                       \
    const unsigned char* vb = kb + 8192;                                       \
    fx4 s[2][2];                                                               \
    s[0][0] = z4; s[0][1] = z4; s[1][0] = z4; s[1][1] = z4;                    \
    __builtin_amdgcn_s_setprio(1);                                             \
    _Pragma("unroll")                                                          \
    for (int tt = 0; tt < 2; ++tt) {                                           \
      _Pragma("unroll")                                                        \
      for (int c = 0; c < 4; ++c) {                                            \
        bfv8 kfr = *(const bfv8*)(kb + tt * 4096 + c * 1024 + lane * 16);      \
        s[0][tt] = mfma16(kfr, qf[0][c], s[0][tt]);                            \
        s[1][tt] = mfma16(kfr, qf[1][c], s[1][tt]);                            \
      }                                                                        \
    }                                                                          \
    __builtin_amdgcn_s_setprio(0);                                             \
    const int kvb = (jb) << 5;                                                 \
    if (kvb + 31 > qw) {                                                       \
      _Pragma("unroll")                                                        \
      for (int qt = 0; qt < 2; ++qt) {                                         \
        const int qrow = qw + qt * 16 + ln16;                                  \
        _Pragma("unroll")                                                      \
        for (int tt = 0; tt < 2; ++tt)                                         \
          _Pragma("unroll")                                                    \
          for (int r = 0; r < 4; ++r) {                                        \
            int kvpos = kvb + 16 * tt + 4 * g + r;                             \
            if (kvpos > qrow) s[qt][tt][r] = -1e30f;                           \
          }                                                                    \
      }                                                                        \
    }                                                                          \
    bfv8 pb[2];                                                                \
    _Pragma("unroll")                                                          \
    for (int qt = 0; qt < 2; ++qt) {                                           \
      fx4 m4 = __builtin_elementwise_max(s[qt][0], s[qt][1]);                  \
      float pm = fmaxf(fmaxf(m4[0], m4[1]), fmaxf(m4[2], m4[3]));              \
      pm = fmaxf(pm, __shfl_xor(pm, 16));                                      \
      pm = fmaxf(pm, __shfl_xor(pm, 32));                                      \
      if (__any(pm > mrun[qt] + 8.0f)) {                                       \
        float mn = fmaxf(mrun[qt], pm);                                        \
        float f  = __builtin_amdgcn_exp2f(mrun[qt] - mn);                      \
        lsum[qt] *= f;                                                         \
        _Pragma("unroll")                                                      \
        for (int dt = 0; dt < 8; ++dt) acc[qt][dt] *= f;                       \
        mrun[qt] = mn;                                                         \
      }                                                                        \
      _Pragma("unroll")                                                        \
      for (int tt = 0; tt < 2; ++tt)                                           \
        _Pragma("unroll")                                                      \
        for (int r = 0; r < 4; ++r)                                            \
          s[qt][tt][r] = __builtin_amdgcn_exp2f(s[qt][tt][r] - mrun[qt]);      \
      fx4 r4 = s[qt][0] + s[qt][1];                                            \
      float rs = (r4[0] + r4[1]) + (r4[2] + r4[3]);                            \
      rs += __shfl_xor(rs, 16);                                                \
      rs += __shfl_xor(rs, 32);                                                \
      lsum[qt] += rs;                                                          \
      bfv8 tt_;                                                                \
      _Pragma("unroll")                                                        \
      for (int j = 0; j < 4; ++j) {                                            \
        tt_[j]     = (__bf16)s[qt][0][j];                                      \
        tt_[j + 4] = (__bf16)s[qt][1][j];                                      \
      }                                                                        \
      pb[qt] = tt_;                                                            \
    }                                                                          \
    __builtin_amdgcn_s_setprio(1);                                             \
    _Pragma("unroll")                                                          \
    for (int dt = 0; dt < 8; ++dt) {                                           \
      bfv8 vfr = *(const bfv8*)(vb + dt * 1024 + lane * 16);                   \
      acc[0][dt] = mfma16(vfr, pb[0], acc[0][dt]);                             \
      acc[1][dt] = mfma16(vfr, pb[1], acc[1][dt]);                             \
    }                                                                          \
    __builtin_amdgcn_s_setprio(0);                                             \
  } while (0)

  for (;;) {  // 1 or 2 pieces
    const int qw = (t << 7) + 32 * w;

    // Q fragments, pre-scaled (32 VGPR)
    bfv8 qf[2][4];
#pragma unroll
    for (int qt = 0; qt < 2; ++qt) {
#pragma unroll
      for (int c = 0; c < 4; ++c) {
        const float* qp = Q + (((size_t)(b * NS + qw + qt * 16 + ln16)) << 7) + 32 * c + 8 * g;
        fx4 a0 = *(const fx4*)qp;
        fx4 a1 = *(const fx4*)(qp + 4);
        bfv8 tt_;
#pragma unroll
        for (int j = 0; j < 4; ++j) {
          tt_[j]     = (__bf16)(a0[j] * SCALE);
          tt_[j + 4] = (__bf16)(a1[j] * SCALE);
        }
        qf[qt][c] = tt_;
      }
    }

    fx4 acc[2][8];
#pragma unroll
    for (int qt = 0; qt < 2; ++qt)
#pragma unroll
      for (int dt = 0; dt < 8; ++dt) acc[qt][dt] = z4;
    float mrun[2] = {-1e30f, -1e30f};
    float lsum[2] = {0.f, 0.f};

    const int nkvw = (qw >> 5) + 1;  // causal limit in 32-units (wave-level)

    // prologue: stage first group into slots 0..3 (piece sizes are mult of 4)
    STAGE(u0 + 0, 0);
    STAGE(u0 + 1, 16384);
    STAGE(u0 + 2, 32768);
    STAGE(u0 + 3, 49152);
    asm volatile("s_waitcnt vmcnt(0)" ::: "memory");
    __builtin_amdgcn_s_barrier();
    asm volatile("" ::: "memory");

    for (int base = u0; base < un; base += 4) {
      if (base + 4 <= nkvw) {
        // fast path: one branch-free block of 4 units -> cross-unit ILP
        COMPUTE(base + 0, 0);
        COMPUTE(base + 1, 16384);
        COMPUTE(base + 2, 32768);
        COMPUTE(base + 3, 49152);
      } else {
        if (base + 0 < nkvw) COMPUTE(base + 0, 0);
        if (base + 1 < nkvw) COMPUTE(base + 1, 16384);
        if (base + 2 < nkvw) COMPUTE(base + 2, 32768);
        if (base + 3 < nkvw) COMPUTE(base + 3, 49152);
      }
      asm volatile("" ::: "memory");
      __builtin_amdgcn_s_barrier();  // A: all waves done reading slots
      if (base + 4 < un) {
        STAGE(base + 4, 0);
        STAGE(base + 5, 16384);
        STAGE(base + 6, 32768);
        STAGE(base + 7, 49152);
        asm volatile("s_waitcnt vmcnt(0)" ::: "memory");
      }
      __builtin_amdgcn_s_barrier();  // B: next group staged
      asm volatile("" ::: "memory");
    }

    // ---- epilogue per mode ----
    if (mode == 0) {  // final: O = acc/l
#pragma unroll
      for (int qt = 0; qt < 2; ++qt) {
        float inv = 1.0f / lsum[qt];
        float* ob = O + (((size_t)(b * NS + qw + qt * 16 + ln16)) << 7) + 4 * g;
#pragma unroll
        for (int dt = 0; dt < 8; ++dt) *(fx4*)(ob + 16 * dt) = acc[qt][dt] * inv;
      }
    } else {
      if (mode == 1) {  // piece0: raw f32 acc -> O (merged later)
#pragma unroll
        for (int qt = 0; qt < 2; ++qt) {
          float* ob = O + (((size_t)(b * NS + qw + qt * 16 + ln16)) << 7) + 4 * g;
#pragma unroll
          for (int dt = 0; dt < 8; ++dt) *(fx4*)(ob + 16 * dt) = acc[qt][dt];
        }
      } else {  // piece1 big-part: bf16 acc -> Pa[b][t-16]
#pragma unroll
        for (int qt = 0; qt < 2; ++qt) {
          const int row = 32 * w + 16 * qt + ln16;
          unsigned short* pp =
              Pa + (((size_t)((b * 16 + (t - 16)) * 128 + row)) << 7) + 4 * g;
#pragma unroll
          for (int dt = 0; dt < 8; ++dt) {
            bfv4 t4;
#pragma unroll
            for (int j = 0; j < 4; ++j) t4[j] = (__bf16)acc[qt][dt][j];
            *(u16x4*)(pp + 16 * dt) = __builtin_bit_cast(u16x4, t4);
          }
        }
      }
      if (g == 0) {  // (m,l) -> Ml[b][t-16][slot][2][128]
        const int slot = mode - 1;
        float* mlp = Ml + (size_t)(((b * 16 + (t - 16)) * 2 + slot) * 2) * 128;
#pragma unroll
        for (int qt = 0; qt < 2; ++qt) {
          const int row = 32 * w + 16 * qt + ln16;
          mlp[row]       = mrun[qt];
          mlp[128 + row] = lsum[qt];
        }
      }
    }

    if (!again) break;
    again = 0;
    t = t1; u0 = 0; un = u1b; mode = 0;
  }
#undef COMPUTE
#undef STAGE
}

// ---------------- merge (r12-verified): piece0 (raw f32 in O) + piece1 (bf16 Pa) ----------------
__global__ void __launch_bounds__(256) merge_kernel(
    float* __restrict__ O, const unsigned short* __restrict__ Pa,
    const float* __restrict__ Ml) {
  const int gid = blockIdx.x * 256 + threadIdx.x;  // 1,048,576 threads exact
  const int d4  = gid & 31;
  const int rg  = gid >> 5;       // 0..32767
  const int b   = rg >> 11;
  const int r2  = rg & 2047;
  const int tt  = r2 >> 7;        // tile t = 16+tt
  const int row = r2 & 127;

  const float* mlp = Ml + (size_t)((b * 16 + tt) * 4) * 128;
  const float m1 = mlp[row],       l1 = mlp[128 + row];
  const float m2 = mlp[256 + row], l2 = mlp[384 + row];
  const float m  = fmaxf(m1, m2);
  const float w1 = __builtin_amdgcn_exp2f(m1 - m);
  const float w2 = __builtin_amdgcn_exp2f(m2 - m);

  float* op = O + (((size_t)(b * NS + (16 + tt) * 128 + row)) << 7) + 4 * d4;
  fx4 a1 = *(const fx4*)op;
  const unsigned short* pp =
      Pa + (((size_t)((b * 16 + tt) * 128 + row)) << 7) + 4 * d4;
  bfv4 a2b = __builtin_bit_cast(bfv4, *(const u16x4*)pp);
  fx4 a2;
#pragma unroll
  for (int j = 0; j < 4; ++j) a2[j] = (float)a2b[j];

  const float inv = 1.0f / (w1 * l1 + w2 * l2);
  fx4 o = (a1 * w1 + a2 * w2) * inv;
  *(fx4*)op = o;
}

extern "C" void kernel_launch(void* const* d_in, const int* in_sizes, int n_in,
                              void* d_out, int out_size, void* d_ws, size_t ws_size,
                              hipStream_t stream) {
  (void)in_sizes; (void)n_in; (void)out_size;
  const float* Q = (const float*)d_in[0];
  const float* K = (const float*)d_in[1];
  const float* V = (const float*)d_in[2];
  float* O = (float*)d_out;

  unsigned short* Kf = (unsigned short*)d_ws;                      // 16 MB @ 0
  unsigned short* Vf = Kf + (size_t)NB * NS * DH;                  // 16 MB @ 16M
  unsigned short* Pa = (unsigned short*)((char*)d_ws + 33554432);  // 8 MB  @ 32M
  float*          Ml = (float*)((char*)d_ws + 41943040);           // 512KB @ 40M

  const size_t NEED = 41943040 + 524288;  // 42,467,328 B (proven available)
  const int split = (ws_size >= NEED) ? 1 : 0;

  prepack_kernel<<<dim3(NB * 64), dim3(256), 0, stream>>>(K, V, Kf, Vf);
  attn_kernel<<<dim3(512), dim3(256), 0, stream>>>(Q, Kf, Vf, O, Pa, Ml, split);
  if (split) merge_kernel<<<dim3(4096), dim3(256), 0, stream>>>(O, Pa, Ml);
}